// Round 1
// baseline (987.094 us; speedup 1.0000x reference)
//
#include <hip/hip_runtime.h>

#define EMBED 128
#define NCODE 10000
#define NSAMP 16384
#define NT 64                 // codes per chunk
#define MT 64                 // samples per workgroup
#define NCHUNK 157            // ceil(10000/64)
#define NCODE_PAD (NCHUNK * NT)   // 10048
#define OUT_ELEMS (NSAMP * EMBED) // 2097152

// Kernel A: cnorm[j] = sum_d C[d][j]^2 ; pad with +huge for j>=NCODE; zero loss slot.
__global__ __launch_bounds__(256) void cnorm_kernel(const float* __restrict__ C,
                                                    float* __restrict__ cnorm,
                                                    float* __restrict__ out) {
    int j = blockIdx.x * 256 + threadIdx.x;
    if (j == 0) out[OUT_ELEMS] = 0.0f;  // loss accumulator (kernel B atomicAdds after)
    if (j >= NCODE_PAD) return;
    if (j >= NCODE) { cnorm[j] = 3.0e38f; return; }
    float s = 0.f;
#pragma unroll 8
    for (int d = 0; d < EMBED; ++d) {
        float v = C[d * NCODE + j];   // coalesced: consecutive j per lane
        s = fmaf(v, v, s);
    }
    cnorm[j] = s;
}

// Kernel B: fused distance-matmul + argmin + gather + output + loss.
// 256 threads: tx = t&15 (code dim), ty = t>>4 (sample dim); 4x4 micro-tile.
__global__ __launch_bounds__(256) void vq_kernel(const float* __restrict__ X,
                                                 const float* __restrict__ C,
                                                 const float* __restrict__ cnorm,
                                                 float* __restrict__ out) {
    __shared__ float S[EMBED][MT];    // samples transposed: S[k][m], 32 KB
    __shared__ float Cc[EMBED][NT];   // code chunk: Cc[k][jj], 32 KB
    __shared__ float cn_s[NT];
    __shared__ int   idx_sm[MT];
    __shared__ float red[4];

    const int t  = threadIdx.x;
    const int tx = t & 15;
    const int ty = t >> 4;
    const int m0 = blockIdx.x * MT;

    // ---- stage samples (once): global float4 coalesced -> LDS transposed ----
    for (int idx = t; idx < MT * (EMBED / 4); idx += 256) {
        int m  = idx >> 5;           // 32 float4 per sample row
        int kq = idx & 31;
        float4 v = *(const float4*)(X + (m0 + m) * EMBED + kq * 4);
        S[kq * 4 + 0][m] = v.x;
        S[kq * 4 + 1][m] = v.y;
        S[kq * 4 + 2][m] = v.z;
        S[kq * 4 + 3][m] = v.w;
    }

    float bestv[4];
    int   bestj[4];
#pragma unroll
    for (int i = 0; i < 4; ++i) { bestv[i] = 3.4e38f; bestj[i] = 0; }

    for (int jc = 0; jc < NCHUNK; ++jc) {
        const int j0 = jc * NT;
        __syncthreads();   // protect Cc/cn_s readers from previous iter
        // ---- stage code chunk: Cc[k][jj] = C[k*NCODE + j0+jj] ----
        if (j0 + NT <= NCODE) {
            for (int idx = t; idx < EMBED * (NT / 4); idx += 256) {
                int k = idx >> 4, jq = idx & 15;
                float4 v = *(const float4*)(C + k * NCODE + j0 + jq * 4);
                *(float4*)&Cc[k][jq * 4] = v;
            }
        } else {
            for (int idx = t; idx < EMBED * NT; idx += 256) {
                int k = idx >> 6, jj = idx & 63;
                int j = j0 + jj;
                Cc[k][jj] = (j < NCODE) ? C[k * NCODE + j] : 0.f;
            }
        }
        if (t < NT) cn_s[t] = cnorm[j0 + t];
        __syncthreads();

        // ---- register-tiled dot products over k = 0..127 ----
        float acc[4][4];
#pragma unroll
        for (int i = 0; i < 4; ++i)
#pragma unroll
            for (int j = 0; j < 4; ++j) acc[i][j] = 0.f;

#pragma unroll 4
        for (int k = 0; k < EMBED; ++k) {
            float4 a = *(const float4*)&S[k][ty * 4];   // broadcast, conflict-free
            float4 b = *(const float4*)&Cc[k][tx * 4];  // 2-way (free)
            acc[0][0] = fmaf(a.x, b.x, acc[0][0]);
            acc[0][1] = fmaf(a.x, b.y, acc[0][1]);
            acc[0][2] = fmaf(a.x, b.z, acc[0][2]);
            acc[0][3] = fmaf(a.x, b.w, acc[0][3]);
            acc[1][0] = fmaf(a.y, b.x, acc[1][0]);
            acc[1][1] = fmaf(a.y, b.y, acc[1][1]);
            acc[1][2] = fmaf(a.y, b.z, acc[1][2]);
            acc[1][3] = fmaf(a.y, b.w, acc[1][3]);
            acc[2][0] = fmaf(a.z, b.x, acc[2][0]);
            acc[2][1] = fmaf(a.z, b.y, acc[2][1]);
            acc[2][2] = fmaf(a.z, b.z, acc[2][2]);
            acc[2][3] = fmaf(a.z, b.w, acc[2][3]);
            acc[3][0] = fmaf(a.w, b.x, acc[3][0]);
            acc[3][1] = fmaf(a.w, b.y, acc[3][1]);
            acc[3][2] = fmaf(a.w, b.z, acc[3][2]);
            acc[3][3] = fmaf(a.w, b.w, acc[3][3]);
        }

        // ---- running argmin: dist = ||c||^2 - 2 s.c (argmin-equivalent) ----
#pragma unroll
        for (int jj = 0; jj < 4; ++jj) {
            int j = j0 + tx * 4 + jj;
            float cn = cn_s[tx * 4 + jj];
#pragma unroll
            for (int i = 0; i < 4; ++i) {
                float d = fmaf(-2.f, acc[i][jj], cn);
                if (d < bestv[i]) { bestv[i] = d; bestj[i] = j; }  // strict <: keeps lowest j on ties
            }
        }
    }

    // ---- reduce across tx (lane bits 0..3), lexicographic (val, idx) ----
#pragma unroll
    for (int off = 1; off < 16; off <<= 1) {
#pragma unroll
        for (int i = 0; i < 4; ++i) {
            float ov = __shfl_xor(bestv[i], off, 64);
            int   oj = __shfl_xor(bestj[i], off, 64);
            if (ov < bestv[i] || (ov == bestv[i] && oj < bestj[i])) {
                bestv[i] = ov; bestj[i] = oj;
            }
        }
    }
    if (tx == 0) {
#pragma unroll
        for (int i = 0; i < 4; ++i) idx_sm[ty * 4 + i] = bestj[i];
    }
    __syncthreads();

    // ---- epilogue: gather quantize, write output, accumulate loss ----
    int m    = t >> 2;
    int d0   = (t & 3) * 32;
    int code = idx_sm[m];
    int obase = (m0 + m) * EMBED;
    float lsum = 0.f;
#pragma unroll 8
    for (int dd = 0; dd < 32; ++dd) {
        int d = d0 + dd;
        float q = C[d * NCODE + code];  // L2/LLC-hot gather
        float x = S[d][m];
        out[obase + d] = q;
        float df = q - x;
        lsum = fmaf(df, df, lsum);
    }

    // block reduction of lsum -> one atomicAdd per block
#pragma unroll
    for (int off = 1; off < 64; off <<= 1) lsum += __shfl_xor(lsum, off, 64);
    if ((t & 63) == 0) red[t >> 6] = lsum;
    __syncthreads();
    if (t == 0) {
        float tot = red[0] + red[1] + red[2] + red[3];
        // loss = q_loss + 0.25*e_loss = 1.25 * mean((q-x)^2)
        atomicAdd(out + OUT_ELEMS, tot * (1.25f / (float)OUT_ELEMS));
    }
}

extern "C" void kernel_launch(void* const* d_in, const int* in_sizes, int n_in,
                              void* d_out, int out_size, void* d_ws, size_t ws_size,
                              hipStream_t stream) {
    const float* X = (const float*)d_in[0];   // (8,64,32,128) fp32 -> (16384,128)
    const float* C = (const float*)d_in[1];   // (128,10000) fp32
    float* out = (float*)d_out;               // 2097152 outputs + 1 loss
    float* cnorm = (float*)d_ws;              // 10048 floats of scratch

    cnorm_kernel<<<(NCODE_PAD + 255) / 256, 256, 0, stream>>>(C, cnorm, out);
    vq_kernel<<<NSAMP / MT, 256, 0, stream>>>(X, C, cnorm, out);
}

// Round 2
// 657.642 us; speedup vs baseline: 1.5010x; 1.5010x over previous
//
#include <hip/hip_runtime.h>

#define EMBED 128
#define NCODE 10000
#define NSAMP 16384
#define MT 64                   // samples per workgroup
#define NTC 256                 // codes per chunk
#define KC 32                   // k-substage depth
#define NSPLIT 2                // codebook splits (blockIdx.y)
#define SPLIT_CODES 5120        // codes per split (padded)
#define SPLIT_CHUNKS (SPLIT_CODES / NTC)   // 20
#define NCODE_PAD (NSPLIT * SPLIT_CODES)   // 10240
#define OUT_ELEMS (NSAMP * EMBED)          // 2097152

// ws layout (floats): [0,10240) cnorm | [10240, +32768) best-val[2][16384]
//                     | next 32768 as int: best-idx[2][16384]
#define WS_VAL_OFF 10240
#define WS_IDX_OFF (10240 + 2 * NSAMP)

// Kernel A: cnorm[j] = sum_d C[d][j]^2, pad with +huge; zero the loss slot.
__global__ __launch_bounds__(256) void cnorm_kernel(const float* __restrict__ C,
                                                    float* __restrict__ cnorm,
                                                    float* __restrict__ out) {
    int j = blockIdx.x * 256 + threadIdx.x;
    if (j == 0) out[OUT_ELEMS] = 0.0f;
    if (j >= NCODE_PAD) return;
    if (j >= NCODE) { cnorm[j] = 3.0e38f; return; }
    float s = 0.f;
#pragma unroll 8
    for (int d = 0; d < EMBED; ++d) {
        float v = C[d * NCODE + j];
        s = fmaf(v, v, s);
    }
    cnorm[j] = s;
}

// Kernel B: distance matmul + per-split argmin.
// 256 threads = 32 tx (codes) x 8 ty (samples); 8x8 micro-tile.
// Each thread's 8 codes: {j0 + tx*4 + c} and {j0 + 128 + tx*4 + c} (2-way bank
// pattern = free; tx*8 contiguous would be 8-way-conflicted).
__global__ __launch_bounds__(256) void vq_kernel(const float* __restrict__ X,
                                                 const float* __restrict__ C,
                                                 const float* __restrict__ cnorm,
                                                 float* __restrict__ wval,
                                                 int* __restrict__ widx) {
    __shared__ float S[EMBED][MT];   // 32 KB, staged once
    __shared__ float Cc[KC][NTC];    // 32 KB, restaged 4x per code-chunk

    const int t  = threadIdx.x;
    const int tx = t & 31;
    const int ty = t >> 5;
    const int m0 = blockIdx.x * MT;
    const int split = blockIdx.y;

    // ---- stage samples once: coalesced float4 read, transposed scatter write
    // (one-time ~32-way write conflicts, ~2k cyc/block: negligible) ----
    for (int idx = t; idx < MT * (EMBED / 4); idx += 256) {
        int m  = idx >> 5;
        int kq = idx & 31;
        float4 v = *(const float4*)(X + (m0 + m) * EMBED + kq * 4);
        S[kq * 4 + 0][m] = v.x;
        S[kq * 4 + 1][m] = v.y;
        S[kq * 4 + 2][m] = v.z;
        S[kq * 4 + 3][m] = v.w;
    }

    float bestv[8];
    int   bestj[8];
#pragma unroll
    for (int i = 0; i < 8; ++i) { bestv[i] = 3.4e38f; bestj[i] = 0; }

    for (int jc = 0; jc < SPLIT_CHUNKS; ++jc) {
        const int j0 = split * SPLIT_CODES + jc * NTC;

        float acc[8][8];
#pragma unroll
        for (int i = 0; i < 8; ++i)
#pragma unroll
            for (int c = 0; c < 8; ++c) acc[i][c] = 0.f;

        for (int ks = 0; ks < EMBED; ks += KC) {
            __syncthreads();   // previous users of Cc done
            // ---- stage Cc[k][jj] = C[(ks+k)*NCODE + j0+jj], zeros past NCODE ----
#pragma unroll
            for (int i = 0; i < 8; ++i) {
                int q  = t + i * 256;
                int k  = q >> 6;
                int jq = q & 63;
                int j  = j0 + jq * 4;
                float4 v;
                if (j < NCODE) v = *(const float4*)(C + (ks + k) * NCODE + j);
                else           v = make_float4(0.f, 0.f, 0.f, 0.f);
                *(float4*)&Cc[k][jq * 4] = v;
            }
            __syncthreads();

#pragma unroll 2
            for (int k = 0; k < KC; ++k) {
                float4 a0 = *(const float4*)&S[ks + k][ty * 8];      // broadcast
                float4 a1 = *(const float4*)&S[ks + k][ty * 8 + 4];
                float4 b0 = *(const float4*)&Cc[k][tx * 4];          // 2-way, free
                float4 b1 = *(const float4*)&Cc[k][128 + tx * 4];
                float av[8] = {a0.x, a0.y, a0.z, a0.w, a1.x, a1.y, a1.z, a1.w};
                float bv[8] = {b0.x, b0.y, b0.z, b0.w, b1.x, b1.y, b1.z, b1.w};
#pragma unroll
                for (int i = 0; i < 8; ++i)
#pragma unroll
                    for (int c = 0; c < 8; ++c)
                        acc[i][c] = fmaf(av[i], bv[c], acc[i][c]);
            }
        }

        // ---- running argmin: dist = ||c||^2 - 2 s.c (argmin-equivalent) ----
#pragma unroll
        for (int g = 0; g < 2; ++g) {
#pragma unroll
            for (int c = 0; c < 4; ++c) {
                int j = j0 + g * 128 + tx * 4 + c;
                float cn = cnorm[j];     // L2-hot scalar load
                int cc = g * 4 + c;
#pragma unroll
                for (int i = 0; i < 8; ++i) {
                    float d = fmaf(-2.f, acc[i][cc], cn);
                    if (d < bestv[i]) { bestv[i] = d; bestj[i] = j; }
                }
            }
        }
    }

    // ---- reduce across tx (lane bits 0..4), lexicographic (val, idx) ----
#pragma unroll
    for (int off = 1; off < 32; off <<= 1) {
#pragma unroll
        for (int i = 0; i < 8; ++i) {
            float ov = __shfl_xor(bestv[i], off, 64);
            int   oj = __shfl_xor(bestj[i], off, 64);
            if (ov < bestv[i] || (ov == bestv[i] && oj < bestj[i])) {
                bestv[i] = ov; bestj[i] = oj;
            }
        }
    }
    if (tx == 0) {
#pragma unroll
        for (int i = 0; i < 8; ++i) {
            int m = m0 + ty * 8 + i;
            wval[split * NSAMP + m] = bestv[i];
            widx[split * NSAMP + m] = bestj[i];
        }
    }
}

// Kernel C: merge split candidates, gather codebook rows, write output, loss.
// 256 threads = 8 samples x 32 lanes; each lane handles 4 consecutive dims.
__global__ __launch_bounds__(256) void finalize_kernel(const float* __restrict__ X,
                                                       const float* __restrict__ C,
                                                       const float* __restrict__ wval,
                                                       const int* __restrict__ widx,
                                                       float* __restrict__ out) {
    __shared__ float red[4];
    const int t = threadIdx.x;
    const int s = t >> 5;
    const int lane = t & 31;
    const int m = blockIdx.x * 8 + s;

    float v0 = wval[m];
    float v1 = wval[NSAMP + m];
    int   i0 = widx[m];
    int   i1 = widx[NSAMP + m];
    // split-0 indices are always lower, so ties -> i0 (first-min semantics)
    int code = (v1 < v0) ? i1 : i0;

    const int d0 = lane * 4;
    float4 x4 = *(const float4*)(X + m * EMBED + d0);
    float4 q;
    q.x = C[(d0 + 0) * NCODE + code];
    q.y = C[(d0 + 1) * NCODE + code];
    q.z = C[(d0 + 2) * NCODE + code];
    q.w = C[(d0 + 3) * NCODE + code];
    *(float4*)(out + m * EMBED + d0) = q;

    float dx = q.x - x4.x, dy = q.y - x4.y, dz = q.z - x4.z, dw = q.w - x4.w;
    float lsum = dx * dx + dy * dy + dz * dz + dw * dw;
#pragma unroll
    for (int off = 1; off < 64; off <<= 1) lsum += __shfl_xor(lsum, off, 64);
    if ((t & 63) == 0) red[t >> 6] = lsum;
    __syncthreads();
    if (t == 0) {
        float tot = red[0] + red[1] + red[2] + red[3];
        // loss = q_loss + 0.25*e_loss = 1.25 * mean((q-x)^2)
        atomicAdd(out + OUT_ELEMS, tot * (1.25f / (float)OUT_ELEMS));
    }
}

extern "C" void kernel_launch(void* const* d_in, const int* in_sizes, int n_in,
                              void* d_out, int out_size, void* d_ws, size_t ws_size,
                              hipStream_t stream) {
    const float* X = (const float*)d_in[0];   // (16384,128) fp32
    const float* C = (const float*)d_in[1];   // (128,10000) fp32
    float* out   = (float*)d_out;             // 2097152 outputs + 1 loss
    float* cnorm = (float*)d_ws;
    float* wval  = (float*)d_ws + WS_VAL_OFF;
    int*   widx  = (int*)d_ws + WS_IDX_OFF;

    cnorm_kernel<<<NCODE_PAD / 256, 256, 0, stream>>>(C, cnorm, out);
    vq_kernel<<<dim3(NSAMP / MT, NSPLIT), 256, 0, stream>>>(X, C, cnorm, wval, widx);
    finalize_kernel<<<NSAMP / 8, 256, 0, stream>>>(X, C, wval, widx, out);
}

// Round 3
// 522.559 us; speedup vs baseline: 1.8890x; 1.2585x over previous
//
#include <hip/hip_runtime.h>

#define EMBED 128
#define NCODE 10000
#define NSAMP 16384
#define NCODE_PAD 10240
#define NBM 128             // m-blocks (16384/128)
#define NBN 80              // n-blocks (10240/128)
#define NKS 4               // k-steps (128/32)
#define OUT_ELEMS (NSAMP * EMBED)
#define TAU 0.02f           // rescue gap threshold (>=40x realistic split-bf16 err)

typedef float f32x4 __attribute__((ext_vector_type(4)));
typedef short s16x8 __attribute__((ext_vector_type(8)));
typedef unsigned short ushort_t;

// ---- ws byte offsets (total ~34.8 MB) ----
#define OFF_XH  0
#define OFF_XL  4194304
#define OFF_CH  8388608
#define OFF_CL  11010048
#define OFF_CT  13631488
#define OFF_CN  18874368
#define OFF_KEY 18915328
#define OFF_C2  29401088
#define OFF_IDX 34643968
#define OFF_RL  34709504
#define OFF_CNT 34775040

__device__ __forceinline__ unsigned short f2bf(float f) {   // RNE fp32->bf16
    unsigned u = __float_as_uint(f);
    return (unsigned short)((u + 0x7fffu + ((u >> 16) & 1u)) >> 16);
}
__device__ __forceinline__ float bf2f(unsigned short h) {
    return __uint_as_float(((unsigned)h) << 16);
}
__device__ __forceinline__ unsigned ordf(float f) {         // order-preserving fp32->u32
    unsigned u = __float_as_uint(f);
    return (u & 0x80000000u) ? ~u : (u | 0x80000000u);
}
__device__ __forceinline__ float unordf(unsigned o) {
    return __uint_as_float((o & 0x80000000u) ? (o ^ 0x80000000u) : ~o);
}

// ---- prep: cnorm (exact fp32) + zero loss/counter ----
__global__ __launch_bounds__(256) void prep_norm(const float* __restrict__ C,
                                                 float* __restrict__ cnorm,
                                                 float* __restrict__ out,
                                                 int* __restrict__ counter) {
    int j = blockIdx.x * 256 + threadIdx.x;
    if (j == 0) { out[OUT_ELEMS] = 0.f; *counter = 0; }
    if (j >= NCODE_PAD) return;
    if (j >= NCODE) { cnorm[j] = 3.0e38f; return; }
    float s = 0.f;
#pragma unroll 8
    for (int d = 0; d < EMBED; ++d) {
        float v = C[d * NCODE + j];
        s = fmaf(v, v, s);
    }
    cnorm[j] = s;
}

// ---- prep: X -> Xh/Xl bf16 pair, pre-swizzled [Bm][ks][quad][ml][j8] ----
__global__ __launch_bounds__(256) void prep_x(const float* __restrict__ X,
                                              ushort_t* __restrict__ Xh,
                                              ushort_t* __restrict__ Xl) {
    int o = blockIdx.x * 256 + threadIdx.x;      // 262144 threads, 8 elems each
    int e0 = o * 8;
    int chunk  = e0 >> 12;                        // Bm*4+ks
    int within = e0 & 4095;
    int q  = within >> 10;
    int ml = (within >> 3) & 127;
    int m  = (chunk >> 2) * 128 + ml;
    int k0 = (chunk & 3) * 32 + q * 8;
    const float* src = X + (size_t)m * EMBED + k0;
    s16x8 vh, vl;
#pragma unroll
    for (int j = 0; j < 8; ++j) {
        float f = src[j];
        unsigned short h = f2bf(f);
        vh[j] = (short)h;
        vl[j] = (short)f2bf(f - bf2f(h));
    }
    *(s16x8*)(Xh + e0) = vh;
    *(s16x8*)(Xl + e0) = vl;
}

// ---- prep: C -> Ch/Cl pre-swizzled (transposed) + CT fp32 [n][k] ----
__global__ __launch_bounds__(256) void prep_c(const float* __restrict__ C,
                                              ushort_t* __restrict__ Ch,
                                              ushort_t* __restrict__ Cl,
                                              float* __restrict__ CT) {
    int o = blockIdx.x * 256 + threadIdx.x;      // 163840 threads
    int e0 = o * 8;
    int chunk  = e0 >> 12;                        // Bn*4+ks
    int within = e0 & 4095;
    int q  = within >> 10;
    int nl = (within >> 3) & 127;
    int n  = (chunk >> 2) * 128 + nl;
    int k0 = (chunk & 3) * 32 + q * 8;
    s16x8 vh, vl;
    float ct[8];
#pragma unroll
    for (int j = 0; j < 8; ++j) {
        int k = k0 + j;
        float f = (n < NCODE) ? C[(size_t)k * NCODE + n] : 0.f;
        unsigned short h = f2bf(f);
        vh[j] = (short)h;
        vl[j] = (short)f2bf(f - bf2f(h));
        ct[j] = f;
    }
    *(s16x8*)(Ch + e0) = vh;
    *(s16x8*)(Cl + e0) = vl;
    *(float4*)(CT + (size_t)n * EMBED + k0)     = make_float4(ct[0], ct[1], ct[2], ct[3]);
    *(float4*)(CT + (size_t)n * EMBED + k0 + 4) = make_float4(ct[4], ct[5], ct[6], ct[7]);
}

// ---- main: split-bf16 MFMA distance matmul + per-block top-2 argmin ----
// 128x128 tile, 4 waves (wave w: mhalf=w&1, nhalf=w>>1), BK=32, 3 MFMA products
// chained into one accumulator: dist_dot = Ah*Bh + Ah*Bl + Al*Bh.
__global__ __launch_bounds__(256) void vq_mfma(const ushort_t* __restrict__ Xh,
                                               const ushort_t* __restrict__ Xl,
                                               const ushort_t* __restrict__ Ch,
                                               const ushort_t* __restrict__ Cl,
                                               const float* __restrict__ cnorm,
                                               unsigned long long* __restrict__ candKey,
                                               unsigned* __restrict__ cand2) {
    __shared__ ushort_t lds[4 * 4096];   // Ah | Al | Bh | Bl, 8 KB each
    const int t     = threadIdx.x;
    const int lane  = t & 63;
    const int wave  = t >> 6;
    const int l15   = lane & 15;
    const int quad  = lane >> 4;
    const int mhalf = wave & 1;
    const int nhalf = wave >> 1;
    const int Bm = blockIdx.x, Bn = blockIdx.y;

    f32x4 acc[4][4];
#pragma unroll
    for (int i = 0; i < 4; ++i)
#pragma unroll
        for (int j2 = 0; j2 < 4; ++j2) acc[i][j2] = (f32x4){0.f, 0.f, 0.f, 0.f};

    float cn[4];
#pragma unroll
    for (int tj = 0; tj < 4; ++tj)
        cn[tj] = cnorm[Bn * 128 + nhalf * 64 + tj * 16 + l15];

    const ushort_t* mysrc =
        (wave == 0) ? Xh + (size_t)Bm * (NKS * 4096) :
        (wave == 1) ? Xl + (size_t)Bm * (NKS * 4096) :
        (wave == 2) ? Ch + (size_t)Bn * (NKS * 4096) :
                      Cl + (size_t)Bn * (NKS * 4096);
    auto ldsw = (__attribute__((address_space(3))) ushort_t*)lds;
    __attribute__((address_space(3))) ushort_t* mydst = ldsw + wave * 4096;

    for (int ks = 0; ks < NKS; ++ks) {
        __syncthreads();
        // wave w stages buffer w: 8 KB contiguous via global_load_lds width=16
        const ushort_t* s = mysrc + ks * 4096 + lane * 8;
#pragma unroll
        for (int i = 0; i < 8; ++i) {
            __builtin_amdgcn_global_load_lds(
                (const __attribute__((address_space(1))) void*)(s + i * 512),
                (__attribute__((address_space(3))) void*)(mydst + i * 512),
                16, 0, 0);
        }
        __syncthreads();

        s16x8 ahf[4], alf[4], bhf[4], blf[4];
#pragma unroll
        for (int x = 0; x < 4; ++x) {
            int ma = quad * 1024 + (mhalf * 64 + x * 16 + l15) * 8;
            int na = quad * 1024 + (nhalf * 64 + x * 16 + l15) * 8;
            ahf[x] = *(const s16x8*)&lds[0 * 4096 + ma];
            alf[x] = *(const s16x8*)&lds[1 * 4096 + ma];
            bhf[x] = *(const s16x8*)&lds[2 * 4096 + na];
            blf[x] = *(const s16x8*)&lds[3 * 4096 + na];
        }
#pragma unroll
        for (int mt = 0; mt < 4; ++mt)
#pragma unroll
            for (int nt = 0; nt < 4; ++nt) {
                acc[mt][nt] = __builtin_amdgcn_mfma_f32_16x16x32_bf16(ahf[mt], bhf[nt], acc[mt][nt], 0, 0, 0);
                acc[mt][nt] = __builtin_amdgcn_mfma_f32_16x16x32_bf16(ahf[mt], blf[nt], acc[mt][nt], 0, 0, 0);
                acc[mt][nt] = __builtin_amdgcn_mfma_f32_16x16x32_bf16(alf[mt], bhf[nt], acc[mt][nt], 0, 0, 0);
            }
    }

    __syncthreads();                  // all frag reads done; reuse LDS for merge
    float* mv1 = (float*)lds;         // [2][128]  (nhalf, m_local)
    int*   mj1 = (int*)(lds + 512);   // byte 1024
    float* mv2 = (float*)(lds + 1024);// byte 2048

    // C/D layout: n = tj*16 + l15, m = mt*16 + quad*4 + r
#pragma unroll
    for (int mt = 0; mt < 4; ++mt)
#pragma unroll
        for (int r = 0; r < 4; ++r) {
            float v1 = 3.4e38f, v2 = 3.4e38f;
            int j1 = 0;
#pragma unroll
            for (int tj = 0; tj < 4; ++tj) {
                float d = fmaf(-2.f, acc[mt][tj][r], cn[tj]);
                int j = Bn * 128 + nhalf * 64 + tj * 16 + l15;
                if (d < v1)      { v2 = v1; v1 = d; j1 = j; }
                else if (d < v2) { v2 = d; }
            }
#pragma unroll
            for (int off = 1; off < 16; off <<= 1) {   // reduce over l15 (same quad)
                float ov1 = __shfl_xor(v1, off, 64);
                int   oj1 = __shfl_xor(j1, off, 64);
                float ov2 = __shfl_xor(v2, off, 64);
                float hi = fmaxf(v1, ov1);
                v2 = fminf(fminf(v2, ov2), hi);
                if (ov1 < v1 || (ov1 == v1 && oj1 < j1)) { v1 = ov1; j1 = oj1; }
            }
            if (l15 == 0) {
                int ml = mhalf * 64 + mt * 16 + quad * 4 + r;
                mv1[nhalf * 128 + ml] = v1;
                mj1[nhalf * 128 + ml] = j1;
                mv2[nhalf * 128 + ml] = v2;
            }
        }
    __syncthreads();
    if (t < 128) {   // merge the two n-halves, emit per-block top-2
        float a1 = mv1[t],      a2 = mv2[t];      int aj = mj1[t];
        float b1 = mv1[128 + t], b2 = mv2[128 + t]; int bj = mj1[128 + t];
        float hi = fmaxf(a1, b1);
        float v2 = fminf(fminf(a2, b2), hi);
        float v1; int j1;
        if (b1 < a1 || (b1 == a1 && bj < aj)) { v1 = b1; j1 = bj; }
        else                                  { v1 = a1; j1 = aj; }
        int m = Bm * 128 + t;
        candKey[(size_t)Bn * NSAMP + m] = ((unsigned long long)ordf(v1) << 32) | (unsigned)j1;
        cand2[(size_t)Bn * NSAMP + m] = ordf(v2);
    }
}

// ---- finalize: global top-2 over 80 block candidates, flag near-ties ----
__global__ __launch_bounds__(256) void finalize_k(const unsigned long long* __restrict__ candKey,
                                                  const unsigned* __restrict__ cand2,
                                                  int* __restrict__ idxf,
                                                  int* __restrict__ rlist,
                                                  int* __restrict__ counter) {
    int m = blockIdx.x * 256 + threadIdx.x;
    unsigned long long best = 0xffffffffffffffffull;
    float v2 = 3.4e38f;
    for (int b = 0; b < NBN; ++b) {
        unsigned long long k = candKey[(size_t)b * NSAMP + m];
        unsigned o2 = cand2[(size_t)b * NSAMP + m];
        if (k < best) {
            if (best != 0xffffffffffffffffull)
                v2 = fminf(v2, unordf((unsigned)(best >> 32)));
            best = k;
            v2 = fminf(v2, unordf(o2));
        } else {
            v2 = fminf(v2, unordf((unsigned)(k >> 32)));
        }
    }
    idxf[m] = (int)(unsigned)(best & 0xffffffffu);
    float v1 = unordf((unsigned)(best >> 32));
    if (v2 - v1 <= TAU) {
        int slot = atomicAdd(counter, 1);
        rlist[slot] = m;
    }
}

// ---- output: gather CT rows, write out, accumulate loss ----
__global__ __launch_bounds__(256) void output_k(const float* __restrict__ X,
                                                const float* __restrict__ CT,
                                                const int* __restrict__ idxf,
                                                float* __restrict__ out) {
    __shared__ float red[4];
    const int t = threadIdx.x;
    const int m = blockIdx.x * 8 + (t >> 5);
    const int l = t & 31;
    int code = idxf[m];
    float4 q = *(const float4*)(CT + (size_t)code * EMBED + l * 4);
    float4 x = *(const float4*)(X + (size_t)m * EMBED + l * 4);
    *(float4*)(out + (size_t)m * EMBED + l * 4) = q;
    float dx = q.x - x.x, dy = q.y - x.y, dz = q.z - x.z, dw = q.w - x.w;
    float lsum = dx * dx + dy * dy + dz * dz + dw * dw;
#pragma unroll
    for (int off = 1; off < 64; off <<= 1) lsum += __shfl_xor(lsum, off, 64);
    if ((t & 63) == 0) red[t >> 6] = lsum;
    __syncthreads();
    if (t == 0)
        atomicAdd(out + OUT_ELEMS,
                  (red[0] + red[1] + red[2] + red[3]) * (1.25f / (float)OUT_ELEMS));
}

// ---- rescue: exact fp32 argmin for flagged (near-tie) samples ----
__global__ __launch_bounds__(256) void rescue_k(const float* __restrict__ X,
                                                const float* __restrict__ CT,
                                                const float* __restrict__ cnorm,
                                                const int* __restrict__ rlist,
                                                const int* __restrict__ counter,
                                                const int* __restrict__ idxf,
                                                float* __restrict__ out) {
    __shared__ float xs[EMBED];
    __shared__ unsigned long long wk[4];
    __shared__ int sjn, sjo;
    const int t = threadIdx.x;
    const int lane = t & 63;
    const int wave = t >> 6;
    int cnt = *counter;
    for (int s = blockIdx.x; s < cnt; s += gridDim.x) {
        int m = rlist[s];
        __syncthreads();
        if (t < 32) {
            float4 v = *(const float4*)(X + (size_t)m * EMBED + t * 4);
            xs[t * 4 + 0] = v.x; xs[t * 4 + 1] = v.y;
            xs[t * 4 + 2] = v.z; xs[t * 4 + 3] = v.w;
        }
        __syncthreads();
        unsigned long long bk = 0xffffffffffffffffull;
        for (int j = t; j < NCODE; j += 256) {
            const float* cr = CT + (size_t)j * EMBED;
            float dot = 0.f;
#pragma unroll 8
            for (int k = 0; k < EMBED; k += 4) {
                float4 c = *(const float4*)(cr + k);
                dot = fmaf(xs[k + 0], c.x, dot);
                dot = fmaf(xs[k + 1], c.y, dot);
                dot = fmaf(xs[k + 2], c.z, dot);
                dot = fmaf(xs[k + 3], c.w, dot);
            }
            float d = fmaf(-2.f, dot, cnorm[j]);
            unsigned long long key = ((unsigned long long)ordf(d) << 32) | (unsigned)j;
            if (key < bk) bk = key;
        }
#pragma unroll
        for (int off = 1; off < 64; off <<= 1) {
            unsigned long long o = __shfl_xor(bk, off, 64);
            if (o < bk) bk = o;
        }
        if (lane == 0) wk[wave] = bk;
        __syncthreads();
        if (t == 0) {
            unsigned long long b = wk[0];
            if (wk[1] < b) b = wk[1];
            if (wk[2] < b) b = wk[2];
            if (wk[3] < b) b = wk[3];
            sjn = (int)(unsigned)(b & 0xffffffffu);
            sjo = idxf[m];
        }
        __syncthreads();
        int jn = sjn, jo = sjo;
        if (jn != jo) {
            float delta = 0.f;
            if (t < 32) {
                float4 qn = *(const float4*)(CT + (size_t)jn * EMBED + t * 4);
                float4 qo = *(const float4*)(CT + (size_t)jo * EMBED + t * 4);
                float x0 = xs[t * 4 + 0], x1 = xs[t * 4 + 1];
                float x2 = xs[t * 4 + 2], x3 = xs[t * 4 + 3];
                *(float4*)(out + (size_t)m * EMBED + t * 4) = qn;
                float dn = (qn.x - x0) * (qn.x - x0) + (qn.y - x1) * (qn.y - x1)
                         + (qn.z - x2) * (qn.z - x2) + (qn.w - x3) * (qn.w - x3);
                float dp = (qo.x - x0) * (qo.x - x0) + (qo.y - x1) * (qo.y - x1)
                         + (qo.z - x2) * (qo.z - x2) + (qo.w - x3) * (qo.w - x3);
                delta = dn - dp;
            }
            if (wave == 0) {
#pragma unroll
                for (int off = 1; off < 64; off <<= 1) delta += __shfl_xor(delta, off, 64);
                if (t == 0)
                    atomicAdd(out + OUT_ELEMS, delta * (1.25f / (float)OUT_ELEMS));
            }
        }
    }
}

extern "C" void kernel_launch(void* const* d_in, const int* in_sizes, int n_in,
                              void* d_out, int out_size, void* d_ws, size_t ws_size,
                              hipStream_t stream) {
    const float* X = (const float*)d_in[0];   // (16384,128) fp32
    const float* C = (const float*)d_in[1];   // (128,10000) fp32
    float* out = (float*)d_out;
    char* ws = (char*)d_ws;

    ushort_t* Xh = (ushort_t*)(ws + OFF_XH);
    ushort_t* Xl = (ushort_t*)(ws + OFF_XL);
    ushort_t* Ch = (ushort_t*)(ws + OFF_CH);
    ushort_t* Cl = (ushort_t*)(ws + OFF_CL);
    float* CT    = (float*)(ws + OFF_CT);
    float* cnorm = (float*)(ws + OFF_CN);
    unsigned long long* candKey = (unsigned long long*)(ws + OFF_KEY);
    unsigned* cand2 = (unsigned*)(ws + OFF_C2);
    int* idxf    = (int*)(ws + OFF_IDX);
    int* rlist   = (int*)(ws + OFF_RL);
    int* counter = (int*)(ws + OFF_CNT);

    prep_norm<<<NCODE_PAD / 256, 256, 0, stream>>>(C, cnorm, out, counter);
    prep_c<<<(NCODE_PAD * 16) / 256, 256, 0, stream>>>(C, Ch, Cl, CT);
    prep_x<<<(NSAMP * 16) / 256, 256, 0, stream>>>(X, Xh, Xl);
    vq_mfma<<<dim3(NBM, NBN), 256, 0, stream>>>(Xh, Xl, Ch, Cl, cnorm, candKey, cand2);
    finalize_k<<<NSAMP / 256, 256, 0, stream>>>(candKey, cand2, idxf, rlist, counter);
    output_k<<<NSAMP / 8, 256, 0, stream>>>(X, CT, idxf, out);
    rescue_k<<<64, 256, 0, stream>>>(X, CT, cnorm, rlist, counter, idxf, out);
}